// Round 18
// baseline (211.466 us; speedup 1.0000x reference)
//
#include <hip/hip_runtime.h>
#include <cstdint>

typedef __bf16 bf16;
typedef __bf16 bf16x8 __attribute__((ext_vector_type(8)));
typedef __bf16 bf16x4 __attribute__((ext_vector_type(4)));
typedef float  f32x4  __attribute__((ext_vector_type(4)));
typedef float  f32x16 __attribute__((ext_vector_type(16)));
typedef int    i32x4  __attribute__((ext_vector_type(4)));

#define DIM   1024
#define LSEQ  2048
#define NH    16
#define HD    64
#define NTOK  4096

#define AS1C(p) ((const __attribute__((address_space(1))) void*)(unsigned long long)(uintptr_t)(p))
#define AS3P(p) ((__attribute__((address_space(3))) void*)(unsigned int)(uintptr_t)(p))
#define SB0 __builtin_amdgcn_sched_barrier(0)
#define CPOL_NT 2   // gfx94x/gfx950 CPol: bit1 = NT (non-temporal)

__device__ __forceinline__ f32x4 mfma16(bf16x8 a, bf16x8 b, f32x4 c) {
  return __builtin_amdgcn_mfma_f32_16x16x32_bf16(a, b, c, 0, 0, 0);
}
__device__ __forceinline__ f32x16 mfma32(bf16x8 a, bf16x8 b, f32x16 c) {
  return __builtin_amdgcn_mfma_f32_32x32x16_bf16(a, b, c, 0, 0, 0);
}
__device__ __forceinline__ int pk2(float a, float b) {
  unsigned short ua = __builtin_bit_cast(unsigned short, (bf16)a);
  unsigned short ub = __builtin_bit_cast(unsigned short, (bf16)b);
  return (int)ua | ((int)ub << 16);
}

// ---------------- x (fp32) -> bf16 ----------------
__global__ __launch_bounds__(256) void k_cvt(const float* __restrict__ x,
                                             bf16* __restrict__ xb) {
  const int i = (blockIdx.x * 256 + threadIdx.x) * 4;
  const f32x4 v = *(const f32x4*)(x + i);
  bf16x4 o;
  o[0] = (bf16)v[0]; o[1] = (bf16)v[1]; o[2] = (bf16)v[2]; o[3] = (bf16)v[3];
  *(bf16x4*)(xb + i) = o;
}

// ---------------- W_eff[o][d] = W[o][d] + 0.5 * sum_r A[d][r] * B[r][o] ----------------
struct WeffArgs {
  const float* W[4]; const float* A[4]; const float* B[4]; bf16* out[4];
};

__global__ __launch_bounds__(256) void k_weff(WeffArgs args) {
  const int o = blockIdx.x;
  const int z = blockIdx.y;
  const float* __restrict__ W  = args.W[z];
  const float* __restrict__ A  = args.A[z];
  const float* __restrict__ Bm = args.B[z];
  bf16* __restrict__ out = args.out[z];
  float Bo[16];
#pragma unroll
  for (int r = 0; r < 16; ++r) Bo[r] = Bm[r * DIM + o];
#pragma unroll
  for (int j = 0; j < 4; ++j) {
    const int d = j * 256 + (int)threadIdx.x;
    const float* Ar = A + (size_t)d * 16;
    float acc = 0.f;
#pragma unroll
    for (int r = 0; r < 16; ++r) acc += Ar[r] * Bo[r];
    out[(size_t)o * DIM + d] = (bf16)(W[(size_t)o * DIM + d] + 0.5f * acc);
  }
}

// ---------------- GEMM, BK=64, XOR-swizzled LDS (T2/T21), BN = NF*32 ----------------
template <int NF, bool F32OUT>
__device__ __forceinline__ void gemm_body64(const bf16* __restrict__ X,
                                            const bf16* __restrict__ W,
                                            const float* __restrict__ bias,
                                            void* __restrict__ out,
                                            float scale, int m0, int n0, int ncol0) {
  constexpr int BN = NF * 32;
  constexpr int BJ = BN / 32;          // B glds per wave
  __shared__ __align__(16) bf16 As[128 * 64];
  __shared__ __align__(16) bf16 Bs[BN * 64];
  const int tid  = threadIdx.x;
  const int lane = tid & 63, w = tid >> 6;
  const int l15 = lane & 15, l4 = lane >> 4;
  const int wr = w >> 1, wc = w & 1;
  const int lr = lane >> 3;
  const int scol = ((lane & 7) ^ lr) * 8;   // swizzled source col (elements)

  f32x4 acc[4][NF] = {};
  const bf16* ag = X + (size_t)m0 * DIM;
  const bf16* bg = W + (size_t)n0 * DIM;

  for (int kt = 0; kt < DIM / 64; ++kt) {
    const int k0 = kt * 64;
#pragma unroll
    for (int j = 0; j < 4; ++j) {
      const int rb = w * 4 + j;
      __builtin_amdgcn_global_load_lds(
          AS1C(ag + (size_t)(rb * 8 + lr) * DIM + k0 + scol),
          AS3P(As + rb * 512), 16, 0, 0);
    }
#pragma unroll
    for (int j = 0; j < BJ; ++j) {
      const int rb = w * BJ + j;
      __builtin_amdgcn_global_load_lds(
          AS1C(bg + (size_t)(rb * 8 + lr) * DIM + k0 + scol),
          AS3P(Bs + rb * 512), 16, 0, 0);
    }
    __syncthreads();
    bf16x8 af[2][4], bfr[2][NF];
#pragma unroll
    for (int ks = 0; ks < 2; ++ks) {
#pragma unroll
      for (int m = 0; m < 4; ++m) {
        const int r = wr * 64 + m * 16 + l15;
        af[ks][m] = *(const bf16x8*)(As + r * 64 + ((ks * 4 + l4) ^ (r & 7)) * 8);
      }
#pragma unroll
      for (int n = 0; n < NF; ++n) {
        const int r = wc * (NF * 16) + n * 16 + l15;
        bfr[ks][n] = *(const bf16x8*)(Bs + r * 64 + ((ks * 4 + l4) ^ (r & 7)) * 8);
      }
    }
#pragma unroll
    for (int m = 0; m < 4; ++m)
#pragma unroll
      for (int n = 0; n < NF; ++n) {
        acc[m][n] = mfma16(af[0][m], bfr[0][n], acc[m][n]);
        acc[m][n] = mfma16(af[1][m], bfr[1][n], acc[m][n]);
      }
    __syncthreads();
  }

#pragma unroll
  for (int m = 0; m < 4; ++m) {
    const int r0 = m0 + wr * 64 + m * 16 + l4 * 4;
#pragma unroll
    for (int n = 0; n < NF; ++n) {
      const int c = ncol0 + wc * (NF * 16) + n * 16 + l15;
      const float bc = bias[c];
#pragma unroll
      for (int t = 0; t < 4; ++t) {
        const float y = (acc[m][n][t] + bc) * scale;
        if constexpr (F32OUT)
          ((float*)out)[(size_t)(r0 + t) * DIM + c] = y;
        else
          ((bf16*)out)[(size_t)(r0 + t) * DIM + c] = (bf16)y;
      }
    }
  }
}

__global__ __launch_bounds__(256) void k_gemm_qkv(
    const bf16* __restrict__ xb, const bf16* __restrict__ weff,
    const float* __restrict__ bq, const float* __restrict__ bk,
    const float* __restrict__ bv,
    bf16* __restrict__ q, bf16* __restrict__ k, bf16* __restrict__ v) {
  const int n0 = blockIdx.y * 128;
  const int z = n0 >> 10;
  const float* bias = (z == 0) ? bq : (z == 1) ? bk : bv;
  bf16* out = (z == 0) ? q : (z == 1) ? k : v;
  const float scale = (z == 0) ? 0.125f : 1.0f;
  gemm_body64<4, false>(xb, weff, bias, out, scale, blockIdx.x * 128, n0, n0 & 1023);
}

__global__ __launch_bounds__(256) void k_gemm_o(
    const bf16* __restrict__ ctx, const bf16* __restrict__ weffo,
    const float* __restrict__ bo, float* __restrict__ out) {
  const int n0 = blockIdx.y * 64;
  gemm_body64<2, true>(ctx, weffo, bo, out, 1.0f, blockIdx.x * 128, n0, n0);
}

// ---------------- K/V fragment pre-pass ----------------
// kf[bh][t][c][lane] (bf16x8): K[t*32+l31][h*64 + c*16 + hi*8 + j]
// vf[bh][t][n*2+c][lane]     : V^T[n*32+l31][t*32 + c*16 + hi*8 + j]
__global__ __launch_bounds__(256) void k_vfrag(const bf16* __restrict__ v,
                                               const bf16* __restrict__ k,
                                               bf16* __restrict__ vf,
                                               bf16* __restrict__ kf) {
  const int lt = blockIdx.x, bh = blockIdx.y;
  const int b = bh >> 4, h = bh & 15;
  __shared__ __align__(16) bf16 tile[64][72];
  const int tid = threadIdx.x;
  const int r = tid >> 2, c0 = (tid & 3) * 16;
  const bf16* src = v + (size_t)(b * LSEQ + lt * 64) * DIM + h * HD;
  *(bf16x8*)(&tile[r][c0])     = *(const bf16x8*)(src + (size_t)r * DIM + c0);
  *(bf16x8*)(&tile[r][c0 + 8]) = *(const bf16x8*)(src + (size_t)r * DIM + c0 + 8);
  __syncthreads();
  const int w = tid >> 6, lane = tid & 63, l31 = lane & 31, hi = lane >> 5;
  {
    const int tt = w >> 1, n = w & 1;
    const int t = lt * 2 + tt;
#pragma unroll
    for (int c = 0; c < 2; ++c) {
      bf16 tmp[8];
#pragma unroll
      for (int j = 0; j < 8; ++j)
        tmp[j] = tile[tt * 32 + c * 16 + hi * 8 + j][n * 32 + l31];
      *(bf16x8*)(vf + ((((size_t)bh * 64 + t) * 4 + n * 2 + c) * 64 + lane) * 8) =
          *(bf16x8*)tmp;
    }
  }
  {
    const int t = lt * 2 + (w & 1);
    const bf16* krow = k + (size_t)(b * LSEQ + t * 32 + l31) * DIM + h * HD + hi * 8;
#pragma unroll
    for (int cc = 0; cc < 2; ++cc) {
      const int c = (w >> 1) + cc * 2;
      *(bf16x8*)(kf + ((((size_t)bh * 64 + t) * 4 + c) * 64 + lane) * 8) =
          *(const bf16x8*)(krow + c * 16);
    }
  }
}

// ---------------- flash attention v8: 256 q-rows/block (2 groups/wave) ----------------
// grid (128): h = x&15, q0 = (x>>4)*256. 8 waves (bb = w>>2, qs = w&3); each
// wave handles q-groups {qs*64, qs*64+32} of batch bb. K/V re-read traffic
// halves vs r15 (256->128 MB). LDS: KV 2 slots (32 KB) + bias 3 slots x 32 KB
// (96 KB) = 128 KB, 1 block/CU, (512,1) full VGPR budget. Steady vmcnt(10) =
// {b(t+1):4, KV(t+1):2, b(t+2):4} in flight. NT bias (r15).
__global__ __launch_bounds__(512, 1) void k_attn(
    const bf16* __restrict__ q, const bf16* __restrict__ kf,
    const bf16* __restrict__ vf, const float* __restrict__ bias,
    bf16* __restrict__ ctx) {
  const int tid = threadIdx.x, w = tid >> 6, lane = tid & 63;
  const int l31 = lane & 31, hi = lane >> 5;
  const int bb = w >> 2, qs = w & 3;
  const int h = blockIdx.x & 15;
  const int q0 = (blockIdx.x >> 4) * 256;

  __shared__ __align__(16) bf16  kls[2][2][2048];   // 16 KB
  __shared__ __align__(16) bf16  vls[2][2][2048];   // 16 KB
  __shared__ __align__(16) float bls[3][8192];      // 96 KB (256 rows x 32 cols)

  // Q fragments for both groups (batch bb, rows q0 + qs*64 + g*32 + l31)
  bf16x8 Qf[2][4];
#pragma unroll
  for (int g = 0; g < 2; ++g) {
    const bf16* qrow =
        q + (size_t)(bb * LSEQ + q0 + qs * 64 + g * 32 + l31) * DIM + h * HD;
#pragma unroll
    for (int c = 0; c < 4; ++c) Qf[g][c] = *(const bf16x8*)(qrow + c * 16 + hi * 8);
  }

  // K/V staging roles (KV ids {2w, 2w+1}; id: batch = kv>>3, V? = (kv>>2)&1, c = kv&3)
  const int kvA = 2 * w, kvB = 2 * w + 1;
  const int kbA = kvA >> 3, vvA = (kvA >> 2) & 1, cA = kvA & 3;
  const int kbB = kvB >> 3, vvB = (kvB >> 2) & 1, cB = kvB & 3;
  const bf16* srcA = (vvA ? vf : kf) + (size_t)(kbA * NH + h) * 64 * 2048 + cA * 512 + lane * 8;
  const bf16* srcB = (vvB ? vf : kf) + (size_t)(kbB * NH + h) * 64 * 2048 + cB * 512 + lane * 8;
  bf16* dstA = (vvA ? &vls[kbA][0][0] : &kls[kbA][0][0]) + cA * 512 + lane * 8;
  bf16* dstB = (vvB ? &vls[kbB][0][0] : &kls[kbB][0][0]) + cB * 512 + lane * 8;

  // bias staging: wave w stages row-blocks 4w..4w+3 (rows q0+32w .. +31)
  const int lr = lane >> 3, lc = lane & 7;
  const float* bs0 = bias + ((size_t)h * LSEQ + q0 + 32 * w + lr) * LSEQ + 4 * (lc ^ lr);
  const float* bs1 = bs0 + (size_t)8 * LSEQ;
  const float* bs2 = bs0 + (size_t)16 * LSEQ;
  const float* bs3 = bs0 + (size_t)24 * LSEQ;
  float* bd0 = &bls[0][0] + (4 * w) * 256 + lane * 4;
  float* bd1 = bd0 + 256;
  float* bd2 = bd0 + 512;
  float* bd3 = bd0 + 768;

  f32x16 acc0[2] = {}, acc1[2] = {};
  float mrun[2] = {-3e38f, -3e38f}, lrun[2] = {0.f, 0.f};

#define STAGEKV(t_, s_)                                                        \
  {                                                                            \
    __builtin_amdgcn_global_load_lds(AS1C(srcA + (size_t)(t_) * 2048),         \
                                     AS3P(dstA + (s_) * 2048), 16, 0, 0);      \
    __builtin_amdgcn_global_load_lds(AS1C(srcB + (size_t)(t_) * 2048),         \
                                     AS3P(dstB + (s_) * 2048), 16, 0, 0);      \
  }
#define STAGEB(t_, s_)                                                         \
  {                                                                            \
    __builtin_amdgcn_global_load_lds(AS1C(bs0 + (size_t)(t_) * 32),            \
                                     AS3P(bd0 + (s_) * 8192), 16, 0, CPOL_NT); \
    __builtin_amdgcn_global_load_lds(AS1C(bs1 + (size_t)(t_) * 32),            \
                                     AS3P(bd1 + (s_) * 8192), 16, 0, CPOL_NT); \
    __builtin_amdgcn_global_load_lds(AS1C(bs2 + (size_t)(t_) * 32),            \
                                     AS3P(bd2 + (s_) * 8192), 16, 0, CPOL_NT); \
    __builtin_amdgcn_global_load_lds(AS1C(bs3 + (size_t)(t_) * 32),            \
                                     AS3P(bd3 + (s_) * 8192), 16, 0, CPOL_NT); \
  }

  // prologue FIFO: KV0(2), b0(4), b1(4)
  STAGEKV(0, 0); SB0;
  STAGEB(0, 0); SB0;
  STAGEB(1, 1); SB0;

  const int sw = (l31 & 7) << 2;
  for (int t = 0; t < 64; ++t) {
    const int slKV = t & 1;
    const int slB = t % 3;
    { const int tn = (t + 1 > 63) ? 63 : t + 1; STAGEKV(tn, (t + 1) & 1); } SB0;
    { const int tn = (t + 2 > 63) ? 63 : t + 2; STAGEB(tn, (t + 2) % 3); } SB0;
    asm volatile("s_waitcnt vmcnt(10)" ::: "memory");
    __builtin_amdgcn_s_barrier();   // KV(t), bias(t) staged (each wave waited)

    bf16x8 Kf[4], Vf[2][2];
    f32x4 br[2][4];
#pragma unroll
    for (int c = 0; c < 4; ++c)
      Kf[c] = *(const bf16x8*)(&kls[bb][slKV][c * 512 + lane * 8]);
#pragma unroll
    for (int u = 0; u < 4; ++u)
      Vf[u >> 1][u & 1] = *(const bf16x8*)(&vls[bb][slKV][u * 512 + lane * 8]);
#pragma unroll
    for (int g = 0; g < 2; ++g) {
      const int rr = qs * 64 + g * 32 + l31;
#pragma unroll
      for (int gg = 0; gg < 4; ++gg)
        br[g][gg] = *(const f32x4*)(
            &bls[slB][rr * 32 + (((gg << 3) | (hi << 2)) ^ sw)]);
    }
    asm volatile("s_waitcnt lgkmcnt(0)" ::: "memory");
    SB0;
    __builtin_amdgcn_s_barrier();   // reads done: slots may be overwritten

    // ---- compute both q-groups ----
#pragma unroll
    for (int g = 0; g < 2; ++g) {
      f32x16 s = {};
#pragma unroll
      for (int c = 0; c < 4; ++c) s = mfma32(Kf[c], Qf[g][c], s);
      float p[16];
#pragma unroll
      for (int r = 0; r < 16; ++r) p[r] = s[r] + br[g][r >> 2][r & 3];
      float m8[8];
#pragma unroll
      for (int i = 0; i < 8; ++i) m8[i] = fmaxf(p[i], p[i + 8]);
      float tm = fmaxf(fmaxf(fmaxf(m8[0], m8[4]), fmaxf(m8[1], m8[5])),
                       fmaxf(fmaxf(m8[2], m8[6]), fmaxf(m8[3], m8[7])));
      tm = fmaxf(tm, __shfl_xor(tm, 32));
      if (!__all(tm <= mrun[g] + 8.0f)) {   // defer-max (T13)
        const float mn = fmaxf(mrun[g], tm);
        const float scl = __expf(mrun[g] - mn);
        mrun[g] = mn;
        lrun[g] *= scl;
#pragma unroll
        for (int r = 0; r < 16; ++r) { acc0[g][r] *= scl; acc1[g][r] *= scl; }
      }
#pragma unroll
      for (int r = 0; r < 16; ++r) p[r] = __expf(p[r] - mrun[g]);
      float s8[8];
#pragma unroll
      for (int i = 0; i < 8; ++i) s8[i] = p[i] + p[i + 8];
      float rs = ((s8[0] + s8[1]) + (s8[2] + s8[3])) + ((s8[4] + s8[5]) + (s8[6] + s8[7]));
      rs += __shfl_xor(rs, 32);
      lrun[g] += rs;
#pragma unroll
      for (int c = 0; c < 2; ++c) {
        const int c8 = c * 8;
        const int A0 = pk2(p[c8 + 0], p[c8 + 1]);
        const int A1 = pk2(p[c8 + 2], p[c8 + 3]);
        const int B0 = pk2(p[c8 + 4], p[c8 + 5]);
        const int B1 = pk2(p[c8 + 6], p[c8 + 7]);
        const int pA0 = __shfl_xor(A0, 32), pA1 = __shfl_xor(A1, 32);
        const int pB0 = __shfl_xor(B0, 32), pB1 = __shfl_xor(B1, 32);
        i32x4 fi;
        fi[0] = hi ? pB0 : A0;
        fi[1] = hi ? pB1 : A1;
        fi[2] = hi ? B0 : pA0;
        fi[3] = hi ? B1 : pA1;
        const bf16x8 pf = __builtin_bit_cast(bf16x8, fi);
        acc0[g] = mfma32(Vf[0][c], pf, acc0[g]);
        acc1[g] = mfma32(Vf[1][c], pf, acc1[g]);
      }
    }
  }
#undef STAGEKV
#undef STAGEB

#pragma unroll
  for (int g = 0; g < 2; ++g) {
    const float inv = 1.0f / lrun[g];
    bf16* cp = ctx + (size_t)(bb * LSEQ + q0 + qs * 64 + g * 32 + l31) * DIM + h * HD;
#pragma unroll
    for (int r = 0; r < 16; ++r) {
      const int dr = (r & 3) + 8 * (r >> 2) + 4 * hi;
      cp[dr]      = (bf16)(acc0[g][r] * inv);
      cp[32 + dr] = (bf16)(acc1[g][r] * inv);
    }
  }
}

// ---------------- launcher ----------------
extern "C" void kernel_launch(void* const* d_in, const int* in_sizes, int n_in,
                              void* d_out, int out_size, void* d_ws, size_t ws_size,
                              hipStream_t stream) {
  const float* x  = (const float*)d_in[0];
  const float* ab = (const float*)d_in[1];
  const float* Wq = (const float*)d_in[2];  const float* bq = (const float*)d_in[3];
  const float* Aq = (const float*)d_in[4];  const float* Bq = (const float*)d_in[5];
  const float* Wk = (const float*)d_in[6];  const float* bk = (const float*)d_in[7];
  const float* Ak = (const float*)d_in[8];  const float* Bk = (const float*)d_in[9];
  const float* Wv = (const float*)d_in[10]; const float* bv = (const float*)d_in[11];
  const float* Av = (const float*)d_in[12]; const float* Bv = (const float*)d_in[13];
  const float* Wo = (const float*)d_in[14]; const float* bo = (const float*)d_in[15];
  const float* Ao = (const float*)d_in[16]; const float* Bo = (const float*)d_in[17];

  uint8_t* ws = (uint8_t*)d_ws;
  const size_t SZ = (size_t)NTOK * DIM * sizeof(bf16);  // 8 MiB
  bf16* xb   = (bf16*)(ws + 0 * SZ);
  bf16* weff = (bf16*)(ws + 1 * SZ);
  bf16* qb   = (bf16*)(ws + 2 * SZ);
  bf16* kb   = (bf16*)(ws + 3 * SZ);
  bf16* vb   = (bf16*)(ws + 4 * SZ);
  bf16* kfb  = (bf16*)(ws + 5 * SZ);
  bf16* vfb  = (bf16*)(ws + 6 * SZ);
  bf16* ctx  = (bf16*)(ws + 7 * SZ);

  k_cvt<<<dim3(NTOK * DIM / 1024), 256, 0, stream>>>(x, xb);

  WeffArgs wa;
  wa.W[0] = Wq; wa.A[0] = Aq; wa.B[0] = Bq; wa.out[0] = weff;
  wa.W[1] = Wk; wa.A[1] = Ak; wa.B[1] = Bk; wa.out[1] = weff + (size_t)DIM * DIM;
  wa.W[2] = Wv; wa.A[2] = Av; wa.B[2] = Bv; wa.out[2] = weff + 2 * (size_t)DIM * DIM;
  wa.W[3] = Wo; wa.A[3] = Ao; wa.B[3] = Bo; wa.out[3] = weff + 3 * (size_t)DIM * DIM;
  k_weff<<<dim3(DIM, 4), 256, 0, stream>>>(wa);

  k_gemm_qkv<<<dim3(32, 24), 256, 0, stream>>>(xb, weff, bq, bk, bv, qb, kb, vb);
  k_vfrag<<<dim3(32, 32), 256, 0, stream>>>(vb, kb, vfb, kfb);
  k_attn<<<dim3(128), 512, 0, stream>>>(qb, kfb, vfb, ab, ctx);
  k_gemm_o<<<dim3(32, 16), 256, 0, stream>>>(ctx, weff + 3 * (size_t)DIM * DIM, bo,
                                             (float*)d_out);
}

// Round 19
// 163.907 us; speedup vs baseline: 1.2902x; 1.2902x over previous
//
#include <hip/hip_runtime.h>
#include <cstdint>

typedef __bf16 bf16;
typedef __bf16 bf16x8 __attribute__((ext_vector_type(8)));
typedef __bf16 bf16x4 __attribute__((ext_vector_type(4)));
typedef float  f32x4  __attribute__((ext_vector_type(4)));
typedef float  f32x16 __attribute__((ext_vector_type(16)));
typedef int    i32x4  __attribute__((ext_vector_type(4)));

#define DIM   1024
#define LSEQ  2048
#define NH    16
#define HD    64
#define NTOK  4096

#define AS1C(p) ((const __attribute__((address_space(1))) void*)(unsigned long long)(uintptr_t)(p))
#define AS3P(p) ((__attribute__((address_space(3))) void*)(unsigned int)(uintptr_t)(p))
#define SB0 __builtin_amdgcn_sched_barrier(0)
#define CPOL_NT 2   // gfx94x/gfx950 CPol: bit1 = NT (non-temporal)

__device__ __forceinline__ f32x4 mfma16(bf16x8 a, bf16x8 b, f32x4 c) {
  return __builtin_amdgcn_mfma_f32_16x16x32_bf16(a, b, c, 0, 0, 0);
}
__device__ __forceinline__ f32x16 mfma32(bf16x8 a, bf16x8 b, f32x16 c) {
  return __builtin_amdgcn_mfma_f32_32x32x16_bf16(a, b, c, 0, 0, 0);
}
__device__ __forceinline__ int pk2(float a, float b) {
  unsigned short ua = __builtin_bit_cast(unsigned short, (bf16)a);
  unsigned short ub = __builtin_bit_cast(unsigned short, (bf16)b);
  return (int)ua | ((int)ub << 16);
}

// ---------------- x (fp32) -> bf16, 8 elem/thread ----------------
__global__ __launch_bounds__(256) void k_cvt(const float* __restrict__ x,
                                             bf16* __restrict__ xb) {
  const int i = (blockIdx.x * 256 + threadIdx.x) * 8;
  const f32x4 v0 = *(const f32x4*)(x + i);
  const f32x4 v1 = *(const f32x4*)(x + i + 4);
  bf16x8 o;
  o[0] = (bf16)v0[0]; o[1] = (bf16)v0[1]; o[2] = (bf16)v0[2]; o[3] = (bf16)v0[3];
  o[4] = (bf16)v1[0]; o[5] = (bf16)v1[1]; o[6] = (bf16)v1[2]; o[7] = (bf16)v1[3];
  *(bf16x8*)(xb + i) = o;
}

// ---------------- W_eff[o][d] = W[o][d] + 0.5 * sum_r A[d][r] * B[r][o] ----------------
struct WeffArgs {
  const float* W[4]; const float* A[4]; const float* B[4]; bf16* out[4];
};

__global__ __launch_bounds__(256) void k_weff(WeffArgs args) {
  const int o = blockIdx.x;
  const int z = blockIdx.y;
  const float* __restrict__ W  = args.W[z];
  const float* __restrict__ A  = args.A[z];
  const float* __restrict__ Bm = args.B[z];
  bf16* __restrict__ out = args.out[z];
  float Bo[16];
#pragma unroll
  for (int r = 0; r < 16; ++r) Bo[r] = Bm[r * DIM + o];
#pragma unroll
  for (int j = 0; j < 4; ++j) {
    const int d = j * 256 + (int)threadIdx.x;
    const float* Ar = A + (size_t)d * 16;
    float acc = 0.f;
#pragma unroll
    for (int r = 0; r < 16; ++r) acc += Ar[r] * Bo[r];
    out[(size_t)o * DIM + d] = (bf16)(W[(size_t)o * DIM + d] + 0.5f * acc);
  }
}

// ---------------- GEMM, BK=64, XOR-swizzled LDS (T2/T21), BN = NF*32 ----------------
template <int NF, bool F32OUT>
__device__ __forceinline__ void gemm_body64(const bf16* __restrict__ X,
                                            const bf16* __restrict__ W,
                                            const float* __restrict__ bias,
                                            void* __restrict__ out,
                                            float scale, int m0, int n0, int ncol0) {
  constexpr int BN = NF * 32;
  constexpr int BJ = BN / 32;          // B glds per wave
  __shared__ __align__(16) bf16 As[128 * 64];
  __shared__ __align__(16) bf16 Bs[BN * 64];
  const int tid  = threadIdx.x;
  const int lane = tid & 63, w = tid >> 6;
  const int l15 = lane & 15, l4 = lane >> 4;
  const int wr = w >> 1, wc = w & 1;
  const int lr = lane >> 3;
  const int scol = ((lane & 7) ^ lr) * 8;   // swizzled source col (elements)

  f32x4 acc[4][NF] = {};
  const bf16* ag = X + (size_t)m0 * DIM;
  const bf16* bg = W + (size_t)n0 * DIM;

  for (int kt = 0; kt < DIM / 64; ++kt) {
    const int k0 = kt * 64;
#pragma unroll
    for (int j = 0; j < 4; ++j) {
      const int rb = w * 4 + j;
      __builtin_amdgcn_global_load_lds(
          AS1C(ag + (size_t)(rb * 8 + lr) * DIM + k0 + scol),
          AS3P(As + rb * 512), 16, 0, 0);
    }
#pragma unroll
    for (int j = 0; j < BJ; ++j) {
      const int rb = w * BJ + j;
      __builtin_amdgcn_global_load_lds(
          AS1C(bg + (size_t)(rb * 8 + lr) * DIM + k0 + scol),
          AS3P(Bs + rb * 512), 16, 0, 0);
    }
    __syncthreads();
    bf16x8 af[2][4], bfr[2][NF];
#pragma unroll
    for (int ks = 0; ks < 2; ++ks) {
#pragma unroll
      for (int m = 0; m < 4; ++m) {
        const int r = wr * 64 + m * 16 + l15;
        af[ks][m] = *(const bf16x8*)(As + r * 64 + ((ks * 4 + l4) ^ (r & 7)) * 8);
      }
#pragma unroll
      for (int n = 0; n < NF; ++n) {
        const int r = wc * (NF * 16) + n * 16 + l15;
        bfr[ks][n] = *(const bf16x8*)(Bs + r * 64 + ((ks * 4 + l4) ^ (r & 7)) * 8);
      }
    }
#pragma unroll
    for (int m = 0; m < 4; ++m)
#pragma unroll
      for (int n = 0; n < NF; ++n) {
        acc[m][n] = mfma16(af[0][m], bfr[0][n], acc[m][n]);
        acc[m][n] = mfma16(af[1][m], bfr[1][n], acc[m][n]);
      }
    __syncthreads();
  }

#pragma unroll
  for (int m = 0; m < 4; ++m) {
    const int r0 = m0 + wr * 64 + m * 16 + l4 * 4;
#pragma unroll
    for (int n = 0; n < NF; ++n) {
      const int c = ncol0 + wc * (NF * 16) + n * 16 + l15;
      const float bc = bias[c];
#pragma unroll
      for (int t = 0; t < 4; ++t) {
        const float y = (acc[m][n][t] + bc) * scale;
        if constexpr (F32OUT)
          ((float*)out)[(size_t)(r0 + t) * DIM + c] = y;
        else
          ((bf16*)out)[(size_t)(r0 + t) * DIM + c] = (bf16)y;
      }
    }
  }
}

__global__ __launch_bounds__(256) void k_gemm_qkv(
    const bf16* __restrict__ xb, const bf16* __restrict__ weff,
    const float* __restrict__ bq, const float* __restrict__ bk,
    const float* __restrict__ bv,
    bf16* __restrict__ q, bf16* __restrict__ k, bf16* __restrict__ v) {
  const int n0 = blockIdx.y * 128;
  const int z = n0 >> 10;
  const float* bias = (z == 0) ? bq : (z == 1) ? bk : bv;
  bf16* out = (z == 0) ? q : (z == 1) ? k : v;
  const float scale = (z == 0) ? 0.125f : 1.0f;
  gemm_body64<4, false>(xb, weff, bias, out, scale, blockIdx.x * 128, n0, n0 & 1023);
}

__global__ __launch_bounds__(256) void k_gemm_o(
    const bf16* __restrict__ ctx, const bf16* __restrict__ weffo,
    const float* __restrict__ bo, float* __restrict__ out) {
  const int n0 = blockIdx.y * 64;
  gemm_body64<2, true>(ctx, weffo, bo, out, 1.0f, blockIdx.x * 128, n0, n0);
}

// ---------------- K/V fragment pre-pass ----------------
// kf[bh][t][c][lane] (bf16x8): K[t*32+l31][h*64 + c*16 + hi*8 + j]
// vf[bh][t][n*2+c][lane]     : V^T[n*32+l31][t*32 + c*16 + hi*8 + j]
__global__ __launch_bounds__(256) void k_vfrag(const bf16* __restrict__ v,
                                               const bf16* __restrict__ k,
                                               bf16* __restrict__ vf,
                                               bf16* __restrict__ kf) {
  const int lt = blockIdx.x, bh = blockIdx.y;
  const int b = bh >> 4, h = bh & 15;
  __shared__ __align__(16) bf16 tile[64][72];
  const int tid = threadIdx.x;
  const int r = tid >> 2, c0 = (tid & 3) * 16;
  const bf16* src = v + (size_t)(b * LSEQ + lt * 64) * DIM + h * HD;
  *(bf16x8*)(&tile[r][c0])     = *(const bf16x8*)(src + (size_t)r * DIM + c0);
  *(bf16x8*)(&tile[r][c0 + 8]) = *(const bf16x8*)(src + (size_t)r * DIM + c0 + 8);
  __syncthreads();
  const int w = tid >> 6, lane = tid & 63, l31 = lane & 31, hi = lane >> 5;
  {
    const int tt = w >> 1, n = w & 1;
    const int t = lt * 2 + tt;
#pragma unroll
    for (int c = 0; c < 2; ++c) {
      bf16 tmp[8];
#pragma unroll
      for (int j = 0; j < 8; ++j)
        tmp[j] = tile[tt * 32 + c * 16 + hi * 8 + j][n * 32 + l31];
      *(bf16x8*)(vf + ((((size_t)bh * 64 + t) * 4 + n * 2 + c) * 64 + lane) * 8) =
          *(bf16x8*)tmp;
    }
  }
  {
    const int t = lt * 2 + (w & 1);
    const bf16* krow = k + (size_t)(b * LSEQ + t * 32 + l31) * DIM + h * HD + hi * 8;
#pragma unroll
    for (int cc = 0; cc < 2; ++cc) {
      const int c = (w >> 1) + cc * 2;
      *(bf16x8*)(kf + ((((size_t)bh * 64 + t) * 4 + c) * 64 + lane) * 8) =
          *(const bf16x8*)(krow + c * 16);
    }
  }
}

// ---------------- flash attention v6 (r15 best: NT bias, 4-slot glds pipe) ----------------
__global__ __launch_bounds__(512, 1) void k_attn(
    const bf16* __restrict__ q, const bf16* __restrict__ kf,
    const bf16* __restrict__ vf, const float* __restrict__ bias,
    bf16* __restrict__ ctx) {
  const int tid = threadIdx.x, w = tid >> 6, lane = tid & 63;
  const int l31 = lane & 31, hi = lane >> 5;
  const int bb = w >> 2, qs = w & 3;
  const int h = blockIdx.x & 15;
  const int q0 = (blockIdx.x >> 4) * 128;

  __shared__ __align__(16) bf16  kls[2][4][2048];   // 32 KB
  __shared__ __align__(16) bf16  vls[2][4][2048];   // 32 KB
  __shared__ __align__(16) float bls[4][4096];      // 64 KB

  const bf16* qrow = q + (size_t)(bb * LSEQ + q0 + qs * 32 + l31) * DIM + h * HD;
  bf16x8 Qf[4];
#pragma unroll
  for (int c = 0; c < 4; ++c) Qf[c] = *(const bf16x8*)(qrow + c * 16 + hi * 8);

  const int kvA = 2 * w, kvB = 2 * w + 1;
  const int kbA = kvA >> 3, vvA = (kvA >> 2) & 1, cA = kvA & 3;
  const int kbB = kvB >> 3, vvB = (kvB >> 2) & 1, cB = kvB & 3;
  const bf16* srcA = (vvA ? vf : kf) + (size_t)(kbA * NH + h) * 64 * 2048 + cA * 512 + lane * 8;
  const bf16* srcB = (vvB ? vf : kf) + (size_t)(kbB * NH + h) * 64 * 2048 + cB * 512 + lane * 8;
  bf16* dstA = (vvA ? &vls[kbA][0][0] : &kls[kbA][0][0]) + cA * 512 + lane * 8;
  bf16* dstB = (vvB ? &vls[kbB][0][0] : &kls[kbB][0][0]) + cB * 512 + lane * 8;
  const int lr = lane >> 3, lc = lane & 7;
  const float* bsA = bias + ((size_t)h * LSEQ + q0 + 16 * w + lr) * LSEQ + 4 * (lc ^ lr);
  const float* bsB = bsA + (size_t)8 * LSEQ;
  float* bdA = &bls[0][0] + (2 * w) * 256 + lane * 4;
  float* bdB = bdA + 256;

  f32x16 acc0 = {}, acc1 = {};
  float mrun = -3e38f, lrun = 0.f;

#define STAGE(t_, s_)                                                          \
  {                                                                            \
    __builtin_amdgcn_global_load_lds(AS1C(srcA + (size_t)(t_) * 2048),         \
                                     AS3P(dstA + (s_) * 2048), 16, 0, 0);      \
    __builtin_amdgcn_global_load_lds(AS1C(srcB + (size_t)(t_) * 2048),         \
                                     AS3P(dstB + (s_) * 2048), 16, 0, 0);      \
    __builtin_amdgcn_global_load_lds(AS1C(bsA + (size_t)(t_) * 32),            \
                                     AS3P(bdA + (s_) * 4096), 16, 0, CPOL_NT); \
    __builtin_amdgcn_global_load_lds(AS1C(bsB + (size_t)(t_) * 32),            \
                                     AS3P(bdB + (s_) * 4096), 16, 0, CPOL_NT); \
  }

  STAGE(0, 0); SB0;
  STAGE(1, 1); SB0;
  STAGE(2, 2); SB0;

  const int rr = qs * 32 + l31;
  const int sw = (l31 & 7) << 2;
  for (int t = 0; t < 64; ++t) {
    const int sl = t & 3;
    const int tn = (t + 3 > 63) ? 63 : t + 3;
    STAGE(tn, (t + 3) & 3); SB0;
    asm volatile("s_waitcnt vmcnt(12)" ::: "memory");
    __builtin_amdgcn_s_barrier();

    bf16x8 Kf[4], Vf[2][2];
    f32x4 br[4];
#pragma unroll
    for (int c = 0; c < 4; ++c)
      Kf[c] = *(const bf16x8*)(&kls[bb][sl][c * 512 + lane * 8]);
#pragma unroll
    for (int u = 0; u < 4; ++u)
      Vf[u >> 1][u & 1] = *(const bf16x8*)(&vls[bb][sl][u * 512 + lane * 8]);
#pragma unroll
    for (int g = 0; g < 4; ++g)
      br[g] = *(const f32x4*)(
          &bls[sl][rr * 32 + (((g << 3) | (hi << 2)) ^ sw)]);
    asm volatile("s_waitcnt lgkmcnt(0)" ::: "memory");
    SB0;
    __builtin_amdgcn_s_barrier();

    f32x16 s = {};
#pragma unroll
    for (int c = 0; c < 4; ++c) s = mfma32(Kf[c], Qf[c], s);
    float p[16];
#pragma unroll
    for (int r = 0; r < 16; ++r) p[r] = s[r] + br[r >> 2][r & 3];
    float m8[8];
#pragma unroll
    for (int i = 0; i < 8; ++i) m8[i] = fmaxf(p[i], p[i + 8]);
    float tm = fmaxf(fmaxf(fmaxf(m8[0], m8[4]), fmaxf(m8[1], m8[5])),
                     fmaxf(fmaxf(m8[2], m8[6]), fmaxf(m8[3], m8[7])));
    tm = fmaxf(tm, __shfl_xor(tm, 32));
    if (!__all(tm <= mrun + 8.0f)) {   // defer-max (T13)
      const float mn = fmaxf(mrun, tm);
      const float scl = __expf(mrun - mn);
      mrun = mn;
      lrun *= scl;
#pragma unroll
      for (int r = 0; r < 16; ++r) { acc0[r] *= scl; acc1[r] *= scl; }
    }
#pragma unroll
    for (int r = 0; r < 16; ++r) p[r] = __expf(p[r] - mrun);
    float s8[8];
#pragma unroll
    for (int i = 0; i < 8; ++i) s8[i] = p[i] + p[i + 8];
    float rs = ((s8[0] + s8[1]) + (s8[2] + s8[3])) + ((s8[4] + s8[5]) + (s8[6] + s8[7]));
    rs += __shfl_xor(rs, 32);
    lrun += rs;
#pragma unroll
    for (int c = 0; c < 2; ++c) {
      const int c8 = c * 8;
      const int A0 = pk2(p[c8 + 0], p[c8 + 1]);
      const int A1 = pk2(p[c8 + 2], p[c8 + 3]);
      const int B0 = pk2(p[c8 + 4], p[c8 + 5]);
      const int B1 = pk2(p[c8 + 6], p[c8 + 7]);
      const int pA0 = __shfl_xor(A0, 32), pA1 = __shfl_xor(A1, 32);
      const int pB0 = __shfl_xor(B0, 32), pB1 = __shfl_xor(B1, 32);
      i32x4 fi;
      fi[0] = hi ? pB0 : A0;
      fi[1] = hi ? pB1 : A1;
      fi[2] = hi ? B0 : pA0;
      fi[3] = hi ? B1 : pA1;
      const bf16x8 pf = __builtin_bit_cast(bf16x8, fi);
      acc0 = mfma32(Vf[0][c], pf, acc0);
      acc1 = mfma32(Vf[1][c], pf, acc1);
    }
  }
#undef STAGE

  const float inv = 1.0f / lrun;
  bf16* cp = ctx + (size_t)(bb * LSEQ + q0 + qs * 32 + l31) * DIM + h * HD;
#pragma unroll
  for (int r = 0; r < 16; ++r) {
    const int dr = (r & 3) + 8 * (r >> 2) + 4 * hi;
    cp[dr]      = (bf16)(acc0[r] * inv);
    cp[32 + dr] = (bf16)(acc1[r] * inv);
  }
}

// ---------------- launcher ----------------
extern "C" void kernel_launch(void* const* d_in, const int* in_sizes, int n_in,
                              void* d_out, int out_size, void* d_ws, size_t ws_size,
                              hipStream_t stream) {
  const float* x  = (const float*)d_in[0];
  const float* ab = (const float*)d_in[1];
  const float* Wq = (const float*)d_in[2];  const float* bq = (const float*)d_in[3];
  const float* Aq = (const float*)d_in[4];  const float* Bq = (const float*)d_in[5];
  const float* Wk = (const float*)d_in[6];  const float* bk = (const float*)d_in[7];
  const float* Ak = (const float*)d_in[8];  const float* Bk = (const float*)d_in[9];
  const float* Wv = (const float*)d_in[10]; const float* bv = (const float*)d_in[11];
  const float* Av = (const float*)d_in[12]; const float* Bv = (const float*)d_in[13];
  const float* Wo = (const float*)d_in[14]; const float* bo = (const float*)d_in[15];
  const float* Ao = (const float*)d_in[16]; const float* Bo = (const float*)d_in[17];

  uint8_t* ws = (uint8_t*)d_ws;
  const size_t SZ = (size_t)NTOK * DIM * sizeof(bf16);  // 8 MiB
  bf16* xb   = (bf16*)(ws + 0 * SZ);
  bf16* weff = (bf16*)(ws + 1 * SZ);
  bf16* qb   = (bf16*)(ws + 2 * SZ);
  bf16* kb   = (bf16*)(ws + 3 * SZ);
  bf16* vb   = (bf16*)(ws + 4 * SZ);
  bf16* kfb  = (bf16*)(ws + 5 * SZ);
  bf16* vfb  = (bf16*)(ws + 6 * SZ);
  bf16* ctx  = (bf16*)(ws + 7 * SZ);

  k_cvt<<<dim3(NTOK * DIM / 2048), 256, 0, stream>>>(x, xb);

  WeffArgs wa;
  wa.W[0] = Wq; wa.A[0] = Aq; wa.B[0] = Bq; wa.out[0] = weff;
  wa.W[1] = Wk; wa.A[1] = Ak; wa.B[1] = Bk; wa.out[1] = weff + (size_t)DIM * DIM;
  wa.W[2] = Wv; wa.A[2] = Av; wa.B[2] = Bv; wa.out[2] = weff + 2 * (size_t)DIM * DIM;
  wa.W[3] = Wo; wa.A[3] = Ao; wa.B[3] = Bo; wa.out[3] = weff + 3 * (size_t)DIM * DIM;
  k_weff<<<dim3(DIM, 4), 256, 0, stream>>>(wa);

  k_gemm_qkv<<<dim3(32, 24), 256, 0, stream>>>(xb, weff, bq, bk, bv, qb, kb, vb);
  k_vfrag<<<dim3(32, 32), 256, 0, stream>>>(vb, kb, vfb, kfb);
  k_attn<<<dim3(256), 512, 0, stream>>>(qb, kfb, vfb, ab, ctx);
  k_gemm_o<<<dim3(32, 16), 256, 0, stream>>>(ctx, weff + 3 * (size_t)DIM * DIM, bo,
                                             (float*)d_out);
}